// Round 6
// baseline (148.187 us; speedup 1.0000x reference)
//
#include <hip/hip_runtime.h>

#define HW    12288
#define Wimg  192
#define Himg  64
#define Wpad  194
#define Ppad  12804   // 66*194

typedef __attribute__((ext_vector_type(8))) __bf16 bf16x8;
typedef __attribute__((ext_vector_type(4))) float  f32x4;

// bf16 <-> fp32 helpers (RNE), header-independent
static __device__ __forceinline__ unsigned short f2bf(float f) {
    union { float f; unsigned int u; } v; v.f = f;
    unsigned int r = v.u + 0x7fffu + ((v.u >> 16) & 1u);
    return (unsigned short)(r >> 16);
}
static __device__ __forceinline__ float bf2f(unsigned short h) {
    union { unsigned int u; float f; } v; v.u = ((unsigned int)h) << 16;
    return v.f;
}
static __device__ __forceinline__ float bflo(unsigned int u) {
    union { unsigned int u; float f; } v; v.u = u << 16; return v.f;
}
static __device__ __forceinline__ float bfhi(unsigned int u) {
    union { unsigned int u; float f; } v; v.u = u & 0xffff0000u; return v.f;
}

// ---------------------------------------------------------------------------
// K1: deformable gather.  R26: LDS layout transposed to pos-major
// s_x[pos][32ch] (stride 80 B = 5 x 16 B -> uniform bank-slot coverage).
// Gather reads become 18 ds_read_b128 (8 ch per read) instead of 144
// ds_read_u16; staging writes become 4 ds_write_b128 instead of 32 b16.
// Math identical (same tap order, same per-channel accumulation order).
// blockIdx.y==192 stripe does the weight prep (fp32 -> bf16 hi/lo split).
// ---------------------------------------------------------------------------
__global__ __launch_bounds__(256, 6) void k_deform(
    const float* __restrict__ x,     // 256 x HW
    const float* __restrict__ xr,    // HW
    const float* __restrict__ rout,  // 256 x 9
    unsigned short* __restrict__ y0, // 256 x HW (bf16)
    const float* __restrict__ wr,    // 128 x 256
    const float* __restrict__ pw1,   // 128 x 128
    const float* __restrict__ pw2,   // 128 x 128
    unsigned short* __restrict__ W1h, unsigned short* __restrict__ W1l,
    unsigned short* __restrict__ W2h, unsigned short* __restrict__ W2l,
    unsigned short* __restrict__ W3h, unsigned short* __restrict__ W3l)
{
    __shared__ __align__(16) unsigned short s_x[240 * 40];  // pos-major, 40-short stride

    const int cblk = blockIdx.x;     // 0..7   (fastest -> XCD id)
    const int tile = blockIdx.y;     // 0..191 deform, 192 = weight prep
    const int tid  = threadIdx.x;

    if (tile == 192) {
        const int base = cblk * 256 + tid;   // 0..2047
        #pragma unroll
        for (int k = 0; k < 32; ++k) {
            const int idx = base + k * 2048;
            float v;
            unsigned short *dh, *dl;
            if (idx < 32768)      { v = wr[idx];         dh = W1h + idx; dl = W1l + idx; }
            else if (idx < 49152) { int u = idx - 32768; v = pw1[u]; dh = W2h + u; dl = W2l + u; }
            else                  { int u = idx - 49152; v = pw2[u]; dh = W3h + u; dl = W3l + u; }
            unsigned short hh = f2bf(v);
            *dh = hh;
            *dl = f2bf(v - bf2f(hh));
        }
        return;
    }

    const int pl   = tid & 63;
    const int wv   = __builtin_amdgcn_readfirstlane(tid >> 6);
    const int h    = tile / 3;
    const int w0   = (tile - h * 3) * 64;
    const int w    = w0 + pl;
    const int gp   = h * Wimg + w;

    int   li[6];
    float gw[6][3];
    const float off = 3.0f / (1.0f + expf(-xr[gp]));

    #pragma unroll
    for (int t = 0; t < 6; ++t) {
        const int xo = (t & 1) ? 1 : -1;
        const int yo = (t >> 1) - 1;
        float ov  = off * (float)xo;
        int   iv  = yo * Wpad;
        int   pre = (h + 1) * Wpad + (w + 1) + xo + iv;
        float after = (float)(pre + iv) + ov;
        int fl = (int)floorf(ov);
        int ce = (int)ceilf(ov);
        int av_f  = min(max(pre + fl + iv, 0), Ppad - 1);
        int av_f1 = min(max(av_f + xo,    0), Ppad - 1);
        int av_c  = min(max(pre + ce + iv, 0), Ppad - 1);
        int av_c1 = min(max(av_c + xo,    0), Ppad - 1);
        float wf  = fabsf(after - (float)av_f);
        float wf1 = fabsf((float)av_f1 - after);
        float wc1 = fabsf(after - (float)av_c1);
        float wc  = fabsf((float)av_c - after);
        float s1 = wf  * (1.0f / Wpad);
        float s2 = wc1 * (1.0f / Wpad);
        int   i4[4] = { av_f, av_f1, av_c1, av_c };
        float w4[4] = { s1 * wf, s1 * wf1, s2 * wc1, s2 * wc };
        int b = min(min(i4[0], i4[1]), min(i4[2], i4[3]));
        const int base = (h + 1 + 2 * yo) * Wpad + w0 - 4;
        li[t] = (t >> 1) * 80 + min(max(b - base, 0), 71);
        #pragma unroll
        for (int s = 0; s < 3; ++s) {
            float ws = 0.0f;
            #pragma unroll
            for (int j = 0; j < 4; ++j)
                ws += (i4[j] == b + s) ? w4[j] : 0.0f;
            int av = b + s;
            int r  = av / Wpad;
            int cc = av - r * Wpad;
            bool inb = (r >= 1) && (r <= Himg) && (cc >= 1) && (cc <= Wimg);
            gw[t][s] = inb ? ws : 0.0f;
        }
    }

    // stage the 3x74 flat windows, pos-major (8 ch packed per b128 write)
    const int jj = tid;
    int  xoff = 0;
    bool valid = false;
    int  rr = 0, jcol = 0;
    if (jj < 222) {
        rr   = jj / 74;
        jcol = jj - rr * 74;
        const int flat = (h + 1 + 2 * (rr - 1)) * Wpad + w0 - 4 + jcol;
        if (flat >= 0 && flat < Ppad) {
            const int r = flat / Wpad;
            const int c = flat - r * Wpad;
            valid = (r >= 1) && (r <= Himg) && (c >= 1) && (c <= Wimg);
            xoff  = valid ? ((r - 1) * Wimg + (c - 1)) : 0;
        }
    }
    const float* xb = x + (size_t)(cblk * 32) * HW;
    if (jj < 222) {
        const int pos = rr * 80 + jcol;
        #pragma unroll
        for (int cb = 0; cb < 4; ++cb) {
            unsigned short tq[8];
            #pragma unroll
            for (int i = 0; i < 8; ++i) {
                float v = valid ? xb[(size_t)(cb * 8 + i) * HW + xoff] : 0.0f;
                tq[i] = f2bf(v);
            }
            uint4 u;
            u.x = (unsigned)tq[0] | ((unsigned)tq[1] << 16);
            u.y = (unsigned)tq[2] | ((unsigned)tq[3] << 16);
            u.z = (unsigned)tq[4] | ((unsigned)tq[5] << 16);
            u.w = (unsigned)tq[6] | ((unsigned)tq[7] << 16);
            *(uint4*)&s_x[pos * 40 + cb * 8] = u;
        }
    }
    __syncthreads();

    // gather: 6 taps x 3 positions, 8 channels per b128 read
    const int c0l  = wv * 8;
    const int cb16 = wv << 3;                 // short offset of this wave's 8 ch
    float acc[8] = {0.f,0.f,0.f,0.f,0.f,0.f,0.f,0.f};
    #pragma unroll
    for (int t = 0; t < 6; ++t) {
        const int k = 3 * (t >> 1) + ((t & 1) ? 2 : 0);
        float part[8];
        #pragma unroll
        for (int s = 0; s < 3; ++s) {
            uint4 u = *(const uint4*)&s_x[(li[t] + s) * 40 + cb16];
            const float g = gw[t][s];
            float v0 = bflo(u.x), v1 = bfhi(u.x), v2 = bflo(u.y), v3 = bfhi(u.y);
            float v4 = bflo(u.z), v5 = bfhi(u.z), v6 = bflo(u.w), v7 = bfhi(u.w);
            if (s == 0) {
                part[0] = g * v0; part[1] = g * v1; part[2] = g * v2; part[3] = g * v3;
                part[4] = g * v4; part[5] = g * v5; part[6] = g * v6; part[7] = g * v7;
            } else {
                part[0] += g * v0; part[1] += g * v1; part[2] += g * v2; part[3] += g * v3;
                part[4] += g * v4; part[5] += g * v5; part[6] += g * v6; part[7] += g * v7;
            }
        }
        const float* rc = rout + (size_t)(cblk * 32 + c0l) * 9 + k;
        #pragma unroll
        for (int i = 0; i < 8; ++i)
            acc[i] += rc[i * 9] * part[i];
    }
    #pragma unroll
    for (int i = 0; i < 8; ++i)
        y0[(size_t)(cblk * 32 + c0l + i) * HW + gp] = f2bf(acc[i]);
}

// ---------------------------------------------------------------------------
// R25: MFMA pointwise GEMM.  Weight fragments hoisted to registers BEFORE the
// barrier (pure dwordx4 loads of pre-split bf16; L2 latency overlaps staging).
// Non-atomic per-block stat partials; consumers fold them.
// Block: 4 waves x (16 o x 32 px).  Grid (384 px-blocks, 2 o-blocks) = 768.
// ---------------------------------------------------------------------------
template <int CIN>
__global__ __launch_bounds__(256, 4) void k_pw_mfma(
    const unsigned short* __restrict__ Aact,  // CIN x HW (bf16)
    const unsigned short* __restrict__ Whi,   // 128 x CIN (bf16)
    const unsigned short* __restrict__ Wlo,   // 128 x CIN (bf16)
    unsigned short* __restrict__ Z,           // 128 x HW (bf16)
    float* __restrict__ part)                 // 384 x 256 {sum,sumsq} partials
{
    constexpr int KC = CIN / 32;
    constexpr int RS = CIN + 8;               // pad keeps b128 16B-aligned
    __shared__ __align__(16) unsigned short s_b[32][RS];

    const int tid = threadIdx.x;
    const int l   = tid & 63;
    const int wv  = tid >> 6;
    const int px0 = blockIdx.x * 32;
    const int o0  = blockIdx.y * 64;

    // ---- stage act tile transposed: s_b[p][c ^ (((p>>4)&3)<<3)] ----
    {
        const int cs  = tid >> 1;             // 0..127
        const int pxb = (tid & 1) << 4;       // 0 or 16
        const int swz = (tid & 1) << 3;       // (p>>4)&3 == tid&1 here
        #pragma unroll
        for (int it = 0; it < CIN / 128; ++it) {
            const int c = cs + it * 128;
            const uint4* src = (const uint4*)(Aact + (size_t)c * HW + px0 + pxb);
            uint4 u0 = src[0];
            uint4 u1 = src[1];
            const int sc = c ^ swz;
            unsigned int wd[8] = {u0.x, u0.y, u0.z, u0.w, u1.x, u1.y, u1.z, u1.w};
            #pragma unroll
            for (int e = 0; e < 8; ++e) {
                s_b[pxb + 2 * e    ][sc] = (unsigned short)(wd[e] & 0xffffu);
                s_b[pxb + 2 * e + 1][sc] = (unsigned short)(wd[e] >> 16);
            }
        }
    }

    // ---- hoist weight fragments into registers (overlaps staging/barrier) ----
    // A-frag layout: row m = l&15, k = (l>>4)*8 + j
    const int orow = o0 + wv * 16 + (l & 15);
    const unsigned short* whp = Whi + (size_t)orow * CIN + ((l >> 4) << 3);
    const unsigned short* wlp = Wlo + (size_t)orow * CIN + ((l >> 4) << 3);
    bf16x8 wh[KC], wl[KC];
    #pragma unroll
    for (int kc = 0; kc < KC; ++kc) {
        wh[kc] = *(const bf16x8*)(whp + kc * 32);
        wl[kc] = *(const bf16x8*)(wlp + kc * 32);
    }

    __syncthreads();

    // ---- MFMA K-loop (fully unrolled, weights in regs) ----
    f32x4 acc[2] = { {0.f, 0.f, 0.f, 0.f}, {0.f, 0.f, 0.f, 0.f} };
    const int prow = l & 15;
    const int kg8  = l >> 4;
    #pragma unroll
    for (int kc = 0; kc < KC; ++kc) {
        #pragma unroll
        for (int ip = 0; ip < 2; ++ip) {
            const int col = kc * 32 + (((kg8 ^ ip) & 3) << 3);
            bf16x8 bfr = *(const bf16x8*)&s_b[ip * 16 + prow][col];
            acc[ip] = __builtin_amdgcn_mfma_f32_16x16x32_bf16(wh[kc], bfr, acc[ip], 0, 0, 0);
            acc[ip] = __builtin_amdgcn_mfma_f32_16x16x32_bf16(wl[kc], bfr, acc[ip], 0, 0, 0);
        }
    }

    // ---- epilogue: store Z (bf16) + per-block partial BN stats (no atomics) ----
    // D layout: col = l&15 (px), row m = (l>>4)*4 + r  (m89-verified)
    float* pp = part + (size_t)blockIdx.x * 256;
    const int obase = o0 + wv * 16 + ((l >> 4) << 2);
    #pragma unroll
    for (int r = 0; r < 4; ++r) {
        const int ch = obase + r;
        float v0 = acc[0][r];
        float v1 = acc[1][r];
        Z[(size_t)ch * HW + px0 + prow]      = f2bf(v0);
        Z[(size_t)ch * HW + px0 + 16 + prow] = f2bf(v1);
        float s = v0 + v1;
        float q = v0 * v0 + v1 * v1;
        s += __shfl_xor(s, 1, 64);  q += __shfl_xor(q, 1, 64);
        s += __shfl_xor(s, 2, 64);  q += __shfl_xor(q, 2, 64);
        s += __shfl_xor(s, 4, 64);  q += __shfl_xor(q, 4, 64);
        s += __shfl_xor(s, 8, 64);  q += __shfl_xor(q, 8, 64);
        if (prow == 0) {
            pp[2 * ch]     = s;
            pp[2 * ch + 1] = q;
        }
    }
}

// ---------------------------------------------------------------------------
// R25: fused stats-fold + BN+LeakyReLU + depthwise 3x3 (zero pad), with the
// channel stripe LDS-staged via uint4 loads.  Block = 1024 px of one channel;
// stages 9 halo rows (3.6 KB), zero-filled OOB rows and zeroed pads.
// ---------------------------------------------------------------------------
__global__ __launch_bounds__(256) void k_dw(
    const unsigned short* __restrict__ Zs,
    const float* __restrict__ part,  // 384 x 256 partials
    const float* __restrict__ g,
    const float* __restrict__ b,
    const float* __restrict__ dwgt,  // 128 x 9
    ushort4* __restrict__ D)
{
    __shared__ float rs[4], rq[4];
    __shared__ __align__(16) unsigned short s_z[9 * 200 + 8];  // 9 rows x (8 pad + 192)
    const int tid = threadIdx.x;
    const int bx  = blockIdx.x;
    const int c   = bx / 12;                  // 12 blocks per channel
    const int m   = bx - c * 12;
    const int g0  = m * 1024;                 // first px of this block
    const int r0  = g0 / Wimg;                // first output row (floor)

    // stage rows r0-1 .. r0+7 at s_z[rr*200 + 8 + col]; pads zeroed
    const unsigned short* zc = Zs + (size_t)c * HW;
    if (tid < 216) {
        const int rr = tid / 24;              // 0..8
        const int cc = (tid - rr * 24) * 8;   // col start (8 shorts / 16 B)
        const int gr = r0 - 1 + rr;
        uint4 u = make_uint4(0u, 0u, 0u, 0u);
        if (gr >= 0 && gr < Himg)
            u = *(const uint4*)(zc + (size_t)gr * Wimg + cc);
        *(uint4*)&s_z[rr * 200 + 8 + cc] = u;
    } else if (tid < 226) {
        // zero the 9 left-pads and the tail (each 8 shorts = 16 B)
        *(uint4*)&s_z[(tid - 216) * 200] = make_uint4(0u, 0u, 0u, 0u);
    }

    // fold this channel's partials
    float s = 0.0f, q = 0.0f;
    for (int bb = tid; bb < 384; bb += 256) {
        const float* pb = part + (size_t)bb * 256 + 2 * c;
        s += pb[0];
        q += pb[1];
    }
    #pragma unroll
    for (int off = 32; off > 0; off >>= 1) {
        s += __shfl_down(s, off, 64);
        q += __shfl_down(q, off, 64);
    }
    if ((tid & 63) == 0) { rs[tid >> 6] = s; rq[tid >> 6] = q; }
    __syncthreads();
    s = rs[0] + rs[1] + rs[2] + rs[3];
    q = rq[0] + rq[1] + rq[2] + rq[3];

    const float mu  = s * (1.0f / HW);
    const float var = q * (1.0f / HW) - mu * mu;
    const float sc  = g[c] * rsqrtf(var + 1e-5f);
    const float sh  = b[c] - mu * sc;

    float wk[9];
    #pragma unroll
    for (int k = 0; k < 9; ++k) wk[k] = dwgt[c * 9 + k];

    const int gg = g0 + tid * 4;              // first of 4 px
    const int h  = gg / Wimg;
    const int w0 = gg - h * Wimg;
    const int lr = h - (r0 - 1);              // local row in s_z (1..7)

    float v[3][6];
    #pragma unroll
    for (int ky = 0; ky < 3; ++ky) {
        const int hh  = h + ky - 1;
        const bool rin = (hh >= 0) && (hh < Himg);
        const unsigned short* sr = &s_z[(lr - 1 + ky) * 200 + 7 + w0];
        #pragma unroll
        for (int j = 0; j < 6; ++j) {
            const int ww = w0 - 1 + j;
            const bool in = rin && (ww >= 0) && (ww < Wimg);
            float z = bf2f(sr[j]);            // staged zeros make OOB reads safe
            float y = z * sc + sh;
            y = (y >= 0.0f) ? y : 0.01f * y;
            v[ky][j] = in ? y : 0.0f;
        }
    }

    ushort4 o;
    float oo[4];
    #pragma unroll
    for (int j = 0; j < 4; ++j) {
        float a = 0.0f;
        #pragma unroll
        for (int ky = 0; ky < 3; ++ky)
            #pragma unroll
            for (int kx = 0; kx < 3; ++kx)
                a += wk[ky * 3 + kx] * v[ky][j + kx];
        oo[j] = a;
    }
    o.x = f2bf(oo[0]); o.y = f2bf(oo[1]); o.z = f2bf(oo[2]); o.w = f2bf(oo[3]);
    D[bx * 256 + tid] = o;
}

// ---------------------------------------------------------------------------
// Fused stats-fold + BN+LeakyReLU, fp32 out.  grid = 1536.
// ---------------------------------------------------------------------------
__global__ __launch_bounds__(256) void k_final(
    const unsigned short* __restrict__ Zs,
    const float* __restrict__ part,  // 384 x 256 partials
    const float* __restrict__ g,
    const float* __restrict__ b,
    float4* __restrict__ out)
{
    __shared__ float rs[4], rq[4];
    const int tid = threadIdx.x;
    const int c   = blockIdx.x / 12;          // 12 blocks per channel

    float s = 0.0f, q = 0.0f;
    for (int bb = tid; bb < 384; bb += 256) {
        const float* pb = part + (size_t)bb * 256 + 2 * c;
        s += pb[0];
        q += pb[1];
    }
    #pragma unroll
    for (int off = 32; off > 0; off >>= 1) {
        s += __shfl_down(s, off, 64);
        q += __shfl_down(q, off, 64);
    }
    if ((tid & 63) == 0) { rs[tid >> 6] = s; rq[tid >> 6] = q; }
    __syncthreads();
    s = rs[0] + rs[1] + rs[2] + rs[3];
    q = rq[0] + rq[1] + rq[2] + rq[3];

    const float mu  = s * (1.0f / HW);
    const float var = q * (1.0f / HW) - mu * mu;
    const float sc  = g[c] * rsqrtf(var + 1e-5f);
    const float sh  = b[c] - mu * sc;

    const int f = blockIdx.x * 256 + tid;
    uint2 a = ((const uint2*)Zs)[f];
    float4 v;
    v.x = bflo(a.x) * sc + sh; v.x = (v.x >= 0.0f) ? v.x : 0.01f * v.x;
    v.y = bfhi(a.x) * sc + sh; v.y = (v.y >= 0.0f) ? v.y : 0.01f * v.y;
    v.z = bflo(a.y) * sc + sh; v.z = (v.z >= 0.0f) ? v.z : 0.01f * v.z;
    v.w = bfhi(a.y) * sc + sh; v.w = (v.w >= 0.0f) ? v.w : 0.01f * v.w;
    out[f] = v;
}

// ---------------------------------------------------------------------------
extern "C" void kernel_launch(void* const* d_in, const int* in_sizes, int n_in,
                              void* d_out, int out_size, void* d_ws, size_t ws_size,
                              hipStream_t stream) {
    const float* x   = (const float*)d_in[0];
    const float* xr  = (const float*)d_in[1];
    const float* ro  = (const float*)d_in[2];
    const float* wr  = (const float*)d_in[3];
    const float* gr  = (const float*)d_in[4];
    const float* br  = (const float*)d_in[5];
    const float* dw1 = (const float*)d_in[6];
    const float* pw1 = (const float*)d_in[7];
    const float* g1  = (const float*)d_in[8];
    const float* b1  = (const float*)d_in[9];
    const float* dw2 = (const float*)d_in[10];
    const float* pw2 = (const float*)d_in[11];
    const float* g2  = (const float*)d_in[12];
    const float* b2  = (const float*)d_in[13];

    unsigned short* WS = (unsigned short*)d_ws;
    unsigned short* y0 = WS;                  // 256 x HW bf16
    unsigned short* Z1 = WS + 3145728;        // 128 x HW bf16
    unsigned short* D  = WS + 4718592;        // 128 x HW bf16 (dw out, reused)
    unsigned short* Z2 = WS + 6291456;
    unsigned short* Z3 = WS + 7864320;
    unsigned short* W1h = WS + 9438720;       // 128x256 bf16 hi
    unsigned short* W1l = WS + 9471488;       // 128x256 bf16 lo
    unsigned short* W2h = WS + 9504256;       // 128x128
    unsigned short* W2l = WS + 9520640;
    unsigned short* W3h = WS + 9537024;
    unsigned short* W3l = WS + 9553408;
    // stat partials (384 x 256 fp32 = 384 KB) live in dead Z-slots:
    float* part1 = (float*)(WS + 6291456);    // Z2 slot (written later by pw2)
    float* part2 = (float*)WS;                // y0 slot (dead after pw1)
    float* part3 = (float*)WS;                // y0 slot (still dead)
    float* out = (float*)d_out;

    k_deform<<<dim3(8, 193), 256, 0, stream>>>(x, xr, ro, y0, wr, pw1, pw2,
                                               W1h, W1l, W2h, W2l, W3h, W3l);
    k_pw_mfma<256><<<dim3(384, 2), 256, 0, stream>>>(y0, W1h, W1l, Z1, part1);
    k_dw<<<1536, 256, 0, stream>>>(Z1, part1, gr, br, dw1, (ushort4*)D);
    k_pw_mfma<128><<<dim3(384, 2), 256, 0, stream>>>(D, W2h, W2l, Z2, part2);
    k_dw<<<1536, 256, 0, stream>>>(Z2, part2, g1, b1, dw2, (ushort4*)D);
    k_pw_mfma<128><<<dim3(384, 2), 256, 0, stream>>>(D, W3h, W3l, Z3, part3);
    k_final<<<1536, 256, 0, stream>>>(Z3, part3, g2, b2, (float4*)out);
}

// Round 7
// 146.857 us; speedup vs baseline: 1.0091x; 1.0091x over previous
//
#include <hip/hip_runtime.h>

#define HW    12288
#define Wimg  192
#define Himg  64
#define Wpad  194
#define Ppad  12804   // 66*194

typedef __attribute__((ext_vector_type(8))) __bf16 bf16x8;
typedef __attribute__((ext_vector_type(4))) float  f32x4;

// bf16 <-> fp32 helpers (RNE), header-independent
static __device__ __forceinline__ unsigned short f2bf(float f) {
    union { float f; unsigned int u; } v; v.f = f;
    unsigned int r = v.u + 0x7fffu + ((v.u >> 16) & 1u);
    return (unsigned short)(r >> 16);
}
static __device__ __forceinline__ float bf2f(unsigned short h) {
    union { unsigned int u; float f; } v; v.u = ((unsigned int)h) << 16;
    return v.f;
}
static __device__ __forceinline__ float bflo(unsigned int u) {
    union { unsigned int u; float f; } v; v.u = u << 16; return v.f;
}
static __device__ __forceinline__ float bfhi(unsigned int u) {
    union { unsigned int u; float f; } v; v.u = u & 0xffff0000u; return v.f;
}

// ---------------------------------------------------------------------------
// K1: deformable gather (flat-space replication, R15-proven math).
// R27: 2-output-row tiles (h, h+2) share 2 of 3 flat window rows -> stage
// 4 rows x 74 pos for 2 rows of output (2 instead of 3 staged rows per
// output row).  Grid (8, 96) = 768 blocks = exactly 3/CU.  Weight prep
// (fp32 -> bf16 hi/lo) distributed: blocks 0..255 do 1 elem per thread.
// Pos-major LDS (R26): s_x[pos][32ch], 18 b128 gather reads per row.
// ---------------------------------------------------------------------------
__global__ __launch_bounds__(256, 6) void k_deform(
    const float* __restrict__ x,     // 256 x HW
    const float* __restrict__ xr,    // HW
    const float* __restrict__ rout,  // 256 x 9
    unsigned short* __restrict__ y0, // 256 x HW (bf16)
    const float* __restrict__ wr,    // 128 x 256
    const float* __restrict__ pw1,   // 128 x 128
    const float* __restrict__ pw2,   // 128 x 128
    unsigned short* __restrict__ W1h, unsigned short* __restrict__ W1l,
    unsigned short* __restrict__ W2h, unsigned short* __restrict__ W2l,
    unsigned short* __restrict__ W3h, unsigned short* __restrict__ W3l)
{
    __shared__ __align__(16) unsigned short s_x[296 * 40];  // 4 rows x 74 pos, 40-short stride

    const int cblk = blockIdx.x;     // 0..7   (fastest -> XCD id)
    const int tile = blockIdx.y;     // 0..95
    const int tid  = threadIdx.x;

    // distributed weight prep: blocks with bid<256 convert one element/thread
    {
        const int bid  = tile * 8 + cblk;
        const int widx = bid * 256 + tid;
        if (widx < 65536) {
            float v;
            unsigned short *dh, *dl;
            if (widx < 32768)      { v = wr[widx];          dh = W1h + widx; dl = W1l + widx; }
            else if (widx < 49152) { int u = widx - 32768;  v = pw1[u]; dh = W2h + u; dl = W2l + u; }
            else                   { int u = widx - 49152;  v = pw2[u]; dh = W3h + u; dl = W3l + u; }
            unsigned short hh = f2bf(v);
            *dh = hh;
            *dl = f2bf(v - bf2f(hh));
        }
    }

    const int pl = tid & 63;
    const int wv = __builtin_amdgcn_readfirstlane(tid >> 6);
    const int hp = tile / 3;                  // 0..31 row-pair id
    const int wt = tile - hp * 3;
    const int w0 = wt * 64;
    const int ha = 4 * (hp >> 1) + (hp & 1);  // output rows ha, ha+2
    const int w  = w0 + pl;

    // ---- stage 4 flat rows (padded rows ha-1+2*rr), pos-major ----
    const float* xb = x + (size_t)(cblk * 32) * HW;
    for (int jj = tid; jj < 296; jj += 256) {
        const int rr   = jj / 74;
        const int jcol = jj - rr * 74;
        const int flat = (ha - 1 + 2 * rr) * Wpad + w0 - 4 + jcol;
        bool valid = false;
        int  xoff  = 0;
        if (flat >= 0 && flat < Ppad) {
            const int r = flat / Wpad;
            const int c = flat - r * Wpad;
            valid = (r >= 1) && (r <= Himg) && (c >= 1) && (c <= Wimg);
            xoff  = valid ? ((r - 1) * Wimg + (c - 1)) : 0;
        }
        #pragma unroll
        for (int cb = 0; cb < 4; ++cb) {
            unsigned short tq[8];
            #pragma unroll
            for (int i = 0; i < 8; ++i) {
                float v = valid ? xb[(size_t)(cb * 8 + i) * HW + xoff] : 0.0f;
                tq[i] = f2bf(v);
            }
            uint4 u;
            u.x = (unsigned)tq[0] | ((unsigned)tq[1] << 16);
            u.y = (unsigned)tq[2] | ((unsigned)tq[3] << 16);
            u.z = (unsigned)tq[4] | ((unsigned)tq[5] << 16);
            u.w = (unsigned)tq[6] | ((unsigned)tq[7] << 16);
            *(uint4*)&s_x[jj * 40 + cb * 8] = u;
        }
    }
    __syncthreads();

    // ---- per output row: tap math + gather (8 ch per b128 read) ----
    const int c0l  = wv * 8;
    const int cb16 = wv << 3;
    for (int r = 0; r < 2; ++r) {
        const int h  = ha + 2 * r;
        const int gp = h * Wimg + w;
        const float off = 3.0f / (1.0f + expf(-xr[gp]));

        int   li[6];
        float gw[6][3];
        #pragma unroll
        for (int t = 0; t < 6; ++t) {
            const int xo = (t & 1) ? 1 : -1;
            const int yo = (t >> 1) - 1;
            float ov  = off * (float)xo;
            int   iv  = yo * Wpad;
            int   pre = (h + 1) * Wpad + (w + 1) + xo + iv;
            float after = (float)(pre + iv) + ov;
            int fl = (int)floorf(ov);
            int ce = (int)ceilf(ov);
            int av_f  = min(max(pre + fl + iv, 0), Ppad - 1);
            int av_f1 = min(max(av_f + xo,    0), Ppad - 1);
            int av_c  = min(max(pre + ce + iv, 0), Ppad - 1);
            int av_c1 = min(max(av_c + xo,    0), Ppad - 1);
            float wf  = fabsf(after - (float)av_f);
            float wf1 = fabsf((float)av_f1 - after);
            float wc1 = fabsf(after - (float)av_c1);
            float wc  = fabsf((float)av_c - after);
            float s1 = wf  * (1.0f / Wpad);
            float s2 = wc1 * (1.0f / Wpad);
            int   i4[4] = { av_f, av_f1, av_c1, av_c };
            float w4[4] = { s1 * wf, s1 * wf1, s2 * wc1, s2 * wc };
            int b = min(min(i4[0], i4[1]), min(i4[2], i4[3]));
            const int base = (h + 1 + 2 * yo) * Wpad + w0 - 4;
            li[t] = (yo + 1 + r) * 74 + min(max(b - base, 0), 71);
            #pragma unroll
            for (int s = 0; s < 3; ++s) {
                float ws = 0.0f;
                #pragma unroll
                for (int j = 0; j < 4; ++j)
                    ws += (i4[j] == b + s) ? w4[j] : 0.0f;
                int av = b + s;
                int rw = av / Wpad;
                int cc = av - rw * Wpad;
                bool inb = (rw >= 1) && (rw <= Himg) && (cc >= 1) && (cc <= Wimg);
                gw[t][s] = inb ? ws : 0.0f;
            }
        }

        float acc[8] = {0.f,0.f,0.f,0.f,0.f,0.f,0.f,0.f};
        #pragma unroll
        for (int t = 0; t < 6; ++t) {
            const int k = 3 * (t >> 1) + ((t & 1) ? 2 : 0);
            float part[8];
            #pragma unroll
            for (int s = 0; s < 3; ++s) {
                uint4 u = *(const uint4*)&s_x[(li[t] + s) * 40 + cb16];
                const float g = gw[t][s];
                float v0 = bflo(u.x), v1 = bfhi(u.x), v2 = bflo(u.y), v3 = bfhi(u.y);
                float v4 = bflo(u.z), v5 = bfhi(u.z), v6 = bflo(u.w), v7 = bfhi(u.w);
                if (s == 0) {
                    part[0] = g * v0; part[1] = g * v1; part[2] = g * v2; part[3] = g * v3;
                    part[4] = g * v4; part[5] = g * v5; part[6] = g * v6; part[7] = g * v7;
                } else {
                    part[0] += g * v0; part[1] += g * v1; part[2] += g * v2; part[3] += g * v3;
                    part[4] += g * v4; part[5] += g * v5; part[6] += g * v6; part[7] += g * v7;
                }
            }
            const float* rc = rout + (size_t)(cblk * 32 + c0l) * 9 + k;
            #pragma unroll
            for (int i = 0; i < 8; ++i)
                acc[i] += rc[i * 9] * part[i];
        }
        #pragma unroll
        for (int i = 0; i < 8; ++i)
            y0[(size_t)(cblk * 32 + c0l + i) * HW + gp] = f2bf(acc[i]);
    }
}

// ---------------------------------------------------------------------------
// R25: MFMA pointwise GEMM.  Weight fragments hoisted to registers BEFORE the
// barrier (pure dwordx4 loads of pre-split bf16; L2 latency overlaps staging).
// Non-atomic per-block stat partials; consumers fold them.
// Block: 4 waves x (16 o x 32 px).  Grid (384 px-blocks, 2 o-blocks) = 768.
// ---------------------------------------------------------------------------
template <int CIN>
__global__ __launch_bounds__(256, 4) void k_pw_mfma(
    const unsigned short* __restrict__ Aact,  // CIN x HW (bf16)
    const unsigned short* __restrict__ Whi,   // 128 x CIN (bf16)
    const unsigned short* __restrict__ Wlo,   // 128 x CIN (bf16)
    unsigned short* __restrict__ Z,           // 128 x HW (bf16)
    float* __restrict__ part)                 // 384 x 256 {sum,sumsq} partials
{
    constexpr int KC = CIN / 32;
    constexpr int RS = CIN + 8;               // pad keeps b128 16B-aligned
    __shared__ __align__(16) unsigned short s_b[32][RS];

    const int tid = threadIdx.x;
    const int l   = tid & 63;
    const int wv  = tid >> 6;
    const int px0 = blockIdx.x * 32;
    const int o0  = blockIdx.y * 64;

    // ---- stage act tile transposed: s_b[p][c ^ (((p>>4)&3)<<3)] ----
    {
        const int cs  = tid >> 1;             // 0..127
        const int pxb = (tid & 1) << 4;       // 0 or 16
        const int swz = (tid & 1) << 3;       // (p>>4)&3 == tid&1 here
        #pragma unroll
        for (int it = 0; it < CIN / 128; ++it) {
            const int c = cs + it * 128;
            const uint4* src = (const uint4*)(Aact + (size_t)c * HW + px0 + pxb);
            uint4 u0 = src[0];
            uint4 u1 = src[1];
            const int sc = c ^ swz;
            unsigned int wd[8] = {u0.x, u0.y, u0.z, u0.w, u1.x, u1.y, u1.z, u1.w};
            #pragma unroll
            for (int e = 0; e < 8; ++e) {
                s_b[pxb + 2 * e    ][sc] = (unsigned short)(wd[e] & 0xffffu);
                s_b[pxb + 2 * e + 1][sc] = (unsigned short)(wd[e] >> 16);
            }
        }
    }

    // ---- hoist weight fragments into registers (overlaps staging/barrier) ----
    // A-frag layout: row m = l&15, k = (l>>4)*8 + j
    const int orow = o0 + wv * 16 + (l & 15);
    const unsigned short* whp = Whi + (size_t)orow * CIN + ((l >> 4) << 3);
    const unsigned short* wlp = Wlo + (size_t)orow * CIN + ((l >> 4) << 3);
    bf16x8 wh[KC], wl[KC];
    #pragma unroll
    for (int kc = 0; kc < KC; ++kc) {
        wh[kc] = *(const bf16x8*)(whp + kc * 32);
        wl[kc] = *(const bf16x8*)(wlp + kc * 32);
    }

    __syncthreads();

    // ---- MFMA K-loop (fully unrolled, weights in regs) ----
    f32x4 acc[2] = { {0.f, 0.f, 0.f, 0.f}, {0.f, 0.f, 0.f, 0.f} };
    const int prow = l & 15;
    const int kg8  = l >> 4;
    #pragma unroll
    for (int kc = 0; kc < KC; ++kc) {
        #pragma unroll
        for (int ip = 0; ip < 2; ++ip) {
            const int col = kc * 32 + (((kg8 ^ ip) & 3) << 3);
            bf16x8 bfr = *(const bf16x8*)&s_b[ip * 16 + prow][col];
            acc[ip] = __builtin_amdgcn_mfma_f32_16x16x32_bf16(wh[kc], bfr, acc[ip], 0, 0, 0);
            acc[ip] = __builtin_amdgcn_mfma_f32_16x16x32_bf16(wl[kc], bfr, acc[ip], 0, 0, 0);
        }
    }

    // ---- epilogue: store Z (bf16) + per-block partial BN stats (no atomics) ----
    // D layout: col = l&15 (px), row m = (l>>4)*4 + r  (m89-verified)
    float* pp = part + (size_t)blockIdx.x * 256;
    const int obase = o0 + wv * 16 + ((l >> 4) << 2);
    #pragma unroll
    for (int r = 0; r < 4; ++r) {
        const int ch = obase + r;
        float v0 = acc[0][r];
        float v1 = acc[1][r];
        Z[(size_t)ch * HW + px0 + prow]      = f2bf(v0);
        Z[(size_t)ch * HW + px0 + 16 + prow] = f2bf(v1);
        float s = v0 + v1;
        float q = v0 * v0 + v1 * v1;
        s += __shfl_xor(s, 1, 64);  q += __shfl_xor(q, 1, 64);
        s += __shfl_xor(s, 2, 64);  q += __shfl_xor(q, 2, 64);
        s += __shfl_xor(s, 4, 64);  q += __shfl_xor(q, 4, 64);
        s += __shfl_xor(s, 8, 64);  q += __shfl_xor(q, 8, 64);
        if (prow == 0) {
            pp[2 * ch]     = s;
            pp[2 * ch + 1] = q;
        }
    }
}

// ---------------------------------------------------------------------------
// R25: fused stats-fold + BN+LeakyReLU + depthwise 3x3 (zero pad), with the
// channel stripe LDS-staged via uint4 loads.  Block = 1024 px of one channel;
// stages 9 halo rows (3.6 KB), zero-filled OOB rows and zeroed pads.
// ---------------------------------------------------------------------------
__global__ __launch_bounds__(256) void k_dw(
    const unsigned short* __restrict__ Zs,
    const float* __restrict__ part,  // 384 x 256 partials
    const float* __restrict__ g,
    const float* __restrict__ b,
    const float* __restrict__ dwgt,  // 128 x 9
    ushort4* __restrict__ D)
{
    __shared__ float rs[4], rq[4];
    __shared__ __align__(16) unsigned short s_z[9 * 200 + 8];  // 9 rows x (8 pad + 192)
    const int tid = threadIdx.x;
    const int bx  = blockIdx.x;
    const int c   = bx / 12;                  // 12 blocks per channel
    const int m   = bx - c * 12;
    const int g0  = m * 1024;                 // first px of this block
    const int r0  = g0 / Wimg;                // first output row (floor)

    // stage rows r0-1 .. r0+7 at s_z[rr*200 + 8 + col]; pads zeroed
    const unsigned short* zc = Zs + (size_t)c * HW;
    if (tid < 216) {
        const int rr = tid / 24;              // 0..8
        const int cc = (tid - rr * 24) * 8;   // col start (8 shorts / 16 B)
        const int gr = r0 - 1 + rr;
        uint4 u = make_uint4(0u, 0u, 0u, 0u);
        if (gr >= 0 && gr < Himg)
            u = *(const uint4*)(zc + (size_t)gr * Wimg + cc);
        *(uint4*)&s_z[rr * 200 + 8 + cc] = u;
    } else if (tid < 226) {
        // zero the 9 left-pads and the tail (each 8 shorts = 16 B)
        *(uint4*)&s_z[(tid - 216) * 200] = make_uint4(0u, 0u, 0u, 0u);
    }

    // fold this channel's partials
    float s = 0.0f, q = 0.0f;
    for (int bb = tid; bb < 384; bb += 256) {
        const float* pb = part + (size_t)bb * 256 + 2 * c;
        s += pb[0];
        q += pb[1];
    }
    #pragma unroll
    for (int off = 32; off > 0; off >>= 1) {
        s += __shfl_down(s, off, 64);
        q += __shfl_down(q, off, 64);
    }
    if ((tid & 63) == 0) { rs[tid >> 6] = s; rq[tid >> 6] = q; }
    __syncthreads();
    s = rs[0] + rs[1] + rs[2] + rs[3];
    q = rq[0] + rq[1] + rq[2] + rq[3];

    const float mu  = s * (1.0f / HW);
    const float var = q * (1.0f / HW) - mu * mu;
    const float sc  = g[c] * rsqrtf(var + 1e-5f);
    const float sh  = b[c] - mu * sc;

    float wk[9];
    #pragma unroll
    for (int k = 0; k < 9; ++k) wk[k] = dwgt[c * 9 + k];

    const int gg = g0 + tid * 4;              // first of 4 px
    const int h  = gg / Wimg;
    const int w0 = gg - h * Wimg;
    const int lr = h - (r0 - 1);              // local row in s_z (1..7)

    float v[3][6];
    #pragma unroll
    for (int ky = 0; ky < 3; ++ky) {
        const int hh  = h + ky - 1;
        const bool rin = (hh >= 0) && (hh < Himg);
        const unsigned short* sr = &s_z[(lr - 1 + ky) * 200 + 7 + w0];
        #pragma unroll
        for (int j = 0; j < 6; ++j) {
            const int ww = w0 - 1 + j;
            const bool in = rin && (ww >= 0) && (ww < Wimg);
            float z = bf2f(sr[j]);            // staged zeros make OOB reads safe
            float y = z * sc + sh;
            y = (y >= 0.0f) ? y : 0.01f * y;
            v[ky][j] = in ? y : 0.0f;
        }
    }

    ushort4 o;
    float oo[4];
    #pragma unroll
    for (int j = 0; j < 4; ++j) {
        float a = 0.0f;
        #pragma unroll
        for (int ky = 0; ky < 3; ++ky)
            #pragma unroll
            for (int kx = 0; kx < 3; ++kx)
                a += wk[ky * 3 + kx] * v[ky][j + kx];
        oo[j] = a;
    }
    o.x = f2bf(oo[0]); o.y = f2bf(oo[1]); o.z = f2bf(oo[2]); o.w = f2bf(oo[3]);
    D[bx * 256 + tid] = o;
}

// ---------------------------------------------------------------------------
// Fused stats-fold + BN+LeakyReLU, fp32 out.  grid = 1536.
// ---------------------------------------------------------------------------
__global__ __launch_bounds__(256) void k_final(
    const unsigned short* __restrict__ Zs,
    const float* __restrict__ part,  // 384 x 256 partials
    const float* __restrict__ g,
    const float* __restrict__ b,
    float4* __restrict__ out)
{
    __shared__ float rs[4], rq[4];
    const int tid = threadIdx.x;
    const int c   = blockIdx.x / 12;          // 12 blocks per channel

    float s = 0.0f, q = 0.0f;
    for (int bb = tid; bb < 384; bb += 256) {
        const float* pb = part + (size_t)bb * 256 + 2 * c;
        s += pb[0];
        q += pb[1];
    }
    #pragma unroll
    for (int off = 32; off > 0; off >>= 1) {
        s += __shfl_down(s, off, 64);
        q += __shfl_down(q, off, 64);
    }
    if ((tid & 63) == 0) { rs[tid >> 6] = s; rq[tid >> 6] = q; }
    __syncthreads();
    s = rs[0] + rs[1] + rs[2] + rs[3];
    q = rq[0] + rq[1] + rq[2] + rq[3];

    const float mu  = s * (1.0f / HW);
    const float var = q * (1.0f / HW) - mu * mu;
    const float sc  = g[c] * rsqrtf(var + 1e-5f);
    const float sh  = b[c] - mu * sc;

    const int f = blockIdx.x * 256 + tid;
    uint2 a = ((const uint2*)Zs)[f];
    float4 v;
    v.x = bflo(a.x) * sc + sh; v.x = (v.x >= 0.0f) ? v.x : 0.01f * v.x;
    v.y = bfhi(a.x) * sc + sh; v.y = (v.y >= 0.0f) ? v.y : 0.01f * v.y;
    v.z = bflo(a.y) * sc + sh; v.z = (v.z >= 0.0f) ? v.z : 0.01f * v.z;
    v.w = bfhi(a.y) * sc + sh; v.w = (v.w >= 0.0f) ? v.w : 0.01f * v.w;
    out[f] = v;
}

// ---------------------------------------------------------------------------
extern "C" void kernel_launch(void* const* d_in, const int* in_sizes, int n_in,
                              void* d_out, int out_size, void* d_ws, size_t ws_size,
                              hipStream_t stream) {
    const float* x   = (const float*)d_in[0];
    const float* xr  = (const float*)d_in[1];
    const float* ro  = (const float*)d_in[2];
    const float* wr  = (const float*)d_in[3];
    const float* gr  = (const float*)d_in[4];
    const float* br  = (const float*)d_in[5];
    const float* dw1 = (const float*)d_in[6];
    const float* pw1 = (const float*)d_in[7];
    const float* g1  = (const float*)d_in[8];
    const float* b1  = (const float*)d_in[9];
    const float* dw2 = (const float*)d_in[10];
    const float* pw2 = (const float*)d_in[11];
    const float* g2  = (const float*)d_in[12];
    const float* b2  = (const float*)d_in[13];

    unsigned short* WS = (unsigned short*)d_ws;
    unsigned short* y0 = WS;                  // 256 x HW bf16
    unsigned short* Z1 = WS + 3145728;        // 128 x HW bf16
    unsigned short* D  = WS + 4718592;        // 128 x HW bf16 (dw out, reused)
    unsigned short* Z2 = WS + 6291456;
    unsigned short* Z3 = WS + 7864320;
    unsigned short* W1h = WS + 9438720;       // 128x256 bf16 hi
    unsigned short* W1l = WS + 9471488;       // 128x256 bf16 lo
    unsigned short* W2h = WS + 9504256;       // 128x128
    unsigned short* W2l = WS + 9520640;
    unsigned short* W3h = WS + 9537024;
    unsigned short* W3l = WS + 9553408;
    // stat partials (384 x 256 fp32 = 384 KB) live in dead Z-slots:
    float* part1 = (float*)(WS + 6291456);    // Z2 slot (written later by pw2)
    float* part2 = (float*)WS;                // y0 slot (dead after pw1)
    float* part3 = (float*)WS;                // y0 slot (still dead)
    float* out = (float*)d_out;

    k_deform<<<dim3(8, 96), 256, 0, stream>>>(x, xr, ro, y0, wr, pw1, pw2,
                                              W1h, W1l, W2h, W2l, W3h, W3l);
    k_pw_mfma<256><<<dim3(384, 2), 256, 0, stream>>>(y0, W1h, W1l, Z1, part1);
    k_dw<<<1536, 256, 0, stream>>>(Z1, part1, gr, br, dw1, (ushort4*)D);
    k_pw_mfma<128><<<dim3(384, 2), 256, 0, stream>>>(D, W2h, W2l, Z2, part2);
    k_dw<<<1536, 256, 0, stream>>>(Z2, part2, g1, b1, dw2, (ushort4*)D);
    k_pw_mfma<128><<<dim3(384, 2), 256, 0, stream>>>(D, W3h, W3l, Z3, part3);
    k_final<<<1536, 256, 0, stream>>>(Z3, part3, g2, b2, (float4*)out);
}

// Round 9
// 146.360 us; speedup vs baseline: 1.0125x; 1.0034x over previous
//
#include <hip/hip_runtime.h>

#define HW    12288
#define Wimg  192
#define Himg  64
#define Wpad  194
#define Ppad  12804   // 66*194

typedef __attribute__((ext_vector_type(8))) __bf16 bf16x8;
typedef __attribute__((ext_vector_type(4))) float  f32x4;

// bf16 <-> fp32 helpers (RNE), header-independent
static __device__ __forceinline__ unsigned short f2bf(float f) {
    union { float f; unsigned int u; } v; v.f = f;
    unsigned int r = v.u + 0x7fffu + ((v.u >> 16) & 1u);
    return (unsigned short)(r >> 16);
}
static __device__ __forceinline__ float bf2f(unsigned short h) {
    union { unsigned int u; float f; } v; v.u = ((unsigned int)h) << 16;
    return v.f;
}
static __device__ __forceinline__ float bflo(unsigned int u) {
    union { unsigned int u; float f; } v; v.u = u << 16; return v.f;
}
static __device__ __forceinline__ float bfhi(unsigned int u) {
    union { unsigned int u; float f; } v; v.u = u & 0xffff0000u; return v.f;
}

// ---------------------------------------------------------------------------
// K1: deformable gather (flat-space replication, R15-proven math).
// R27: 2-output-row tiles (h, h+2) share 2 of 3 flat window rows -> stage
// 4 rows x 74 pos for 2 rows of output.  Grid (8, 96) = 768 blocks = 3/CU.
// Weight prep (fp32 -> bf16 hi/lo) distributed: blocks 0..255, 1 elem/thread.
// Pos-major LDS (R26): s_x[pos][32ch], 18 b128 gather reads per row.
// ---------------------------------------------------------------------------
__global__ __launch_bounds__(256, 6) void k_deform(
    const float* __restrict__ x,     // 256 x HW
    const float* __restrict__ xr,    // HW
    const float* __restrict__ rout,  // 256 x 9
    unsigned short* __restrict__ y0, // 256 x HW (bf16)
    const float* __restrict__ wr,    // 128 x 256
    const float* __restrict__ pw1,   // 128 x 128
    const float* __restrict__ pw2,   // 128 x 128
    unsigned short* __restrict__ W1h, unsigned short* __restrict__ W1l,
    unsigned short* __restrict__ W2h, unsigned short* __restrict__ W2l,
    unsigned short* __restrict__ W3h, unsigned short* __restrict__ W3l)
{
    __shared__ __align__(16) unsigned short s_x[296 * 40];  // 4 rows x 74 pos, 40-short stride

    const int cblk = blockIdx.x;     // 0..7   (fastest -> XCD id)
    const int tile = blockIdx.y;     // 0..95
    const int tid  = threadIdx.x;

    // distributed weight prep: blocks with bid<256 convert one element/thread
    {
        const int bid  = tile * 8 + cblk;
        const int widx = bid * 256 + tid;
        if (widx < 65536) {
            float v;
            unsigned short *dh, *dl;
            if (widx < 32768)      { v = wr[widx];          dh = W1h + widx; dl = W1l + widx; }
            else if (widx < 49152) { int u = widx - 32768;  v = pw1[u]; dh = W2h + u; dl = W2l + u; }
            else                   { int u = widx - 49152;  v = pw2[u]; dh = W3h + u; dl = W3l + u; }
            unsigned short hh = f2bf(v);
            *dh = hh;
            *dl = f2bf(v - bf2f(hh));
        }
    }

    const int pl = tid & 63;
    const int wv = __builtin_amdgcn_readfirstlane(tid >> 6);
    const int hp = tile / 3;                  // 0..31 row-pair id
    const int wt = tile - hp * 3;
    const int w0 = wt * 64;
    const int ha = 4 * (hp >> 1) + (hp & 1);  // output rows ha, ha+2
    const int w  = w0 + pl;

    // ---- stage 4 flat rows (padded rows ha-1+2*rr), pos-major ----
    const float* xb = x + (size_t)(cblk * 32) * HW;
    for (int jj = tid; jj < 296; jj += 256) {
        const int rr   = jj / 74;
        const int jcol = jj - rr * 74;
        const int flat = (ha - 1 + 2 * rr) * Wpad + w0 - 4 + jcol;
        bool valid = false;
        int  xoff  = 0;
        if (flat >= 0 && flat < Ppad) {
            const int r = flat / Wpad;
            const int c = flat - r * Wpad;
            valid = (r >= 1) && (r <= Himg) && (c >= 1) && (c <= Wimg);
            xoff  = valid ? ((r - 1) * Wimg + (c - 1)) : 0;
        }
        #pragma unroll
        for (int cb = 0; cb < 4; ++cb) {
            unsigned short tq[8];
            #pragma unroll
            for (int i = 0; i < 8; ++i) {
                float v = valid ? xb[(size_t)(cb * 8 + i) * HW + xoff] : 0.0f;
                tq[i] = f2bf(v);
            }
            uint4 u;
            u.x = (unsigned)tq[0] | ((unsigned)tq[1] << 16);
            u.y = (unsigned)tq[2] | ((unsigned)tq[3] << 16);
            u.z = (unsigned)tq[4] | ((unsigned)tq[5] << 16);
            u.w = (unsigned)tq[6] | ((unsigned)tq[7] << 16);
            *(uint4*)&s_x[jj * 40 + cb * 8] = u;
        }
    }
    __syncthreads();

    // ---- per output row: tap math + gather (8 ch per b128 read) ----
    const int c0l  = wv * 8;
    const int cb16 = wv << 3;
    for (int r = 0; r < 2; ++r) {
        const int h  = ha + 2 * r;
        const int gp = h * Wimg + w;
        const float off = 3.0f / (1.0f + expf(-xr[gp]));

        int   li[6];
        float gw[6][3];
        #pragma unroll
        for (int t = 0; t < 6; ++t) {
            const int xo = (t & 1) ? 1 : -1;
            const int yo = (t >> 1) - 1;
            float ov  = off * (float)xo;
            int   iv  = yo * Wpad;
            int   pre = (h + 1) * Wpad + (w + 1) + xo + iv;
            float after = (float)(pre + iv) + ov;
            int fl = (int)floorf(ov);
            int ce = (int)ceilf(ov);
            int av_f  = min(max(pre + fl + iv, 0), Ppad - 1);
            int av_f1 = min(max(av_f + xo,    0), Ppad - 1);
            int av_c  = min(max(pre + ce + iv, 0), Ppad - 1);
            int av_c1 = min(max(av_c + xo,    0), Ppad - 1);
            float wf  = fabsf(after - (float)av_f);
            float wf1 = fabsf((float)av_f1 - after);
            float wc1 = fabsf(after - (float)av_c1);
            float wc  = fabsf((float)av_c - after);
            float s1 = wf  * (1.0f / Wpad);
            float s2 = wc1 * (1.0f / Wpad);
            int   i4[4] = { av_f, av_f1, av_c1, av_c };
            float w4[4] = { s1 * wf, s1 * wf1, s2 * wc1, s2 * wc };
            int b = min(min(i4[0], i4[1]), min(i4[2], i4[3]));
            const int base = (h + 1 + 2 * yo) * Wpad + w0 - 4;
            li[t] = (yo + 1 + r) * 74 + min(max(b - base, 0), 71);
            #pragma unroll
            for (int s = 0; s < 3; ++s) {
                float ws = 0.0f;
                #pragma unroll
                for (int j = 0; j < 4; ++j)
                    ws += (i4[j] == b + s) ? w4[j] : 0.0f;
                int av = b + s;
                int rw = av / Wpad;
                int cc = av - rw * Wpad;
                bool inb = (rw >= 1) && (rw <= Himg) && (cc >= 1) && (cc <= Wimg);
                gw[t][s] = inb ? ws : 0.0f;
            }
        }

        float acc[8] = {0.f,0.f,0.f,0.f,0.f,0.f,0.f,0.f};
        #pragma unroll
        for (int t = 0; t < 6; ++t) {
            const int k = 3 * (t >> 1) + ((t & 1) ? 2 : 0);
            float part[8];
            #pragma unroll
            for (int s = 0; s < 3; ++s) {
                uint4 u = *(const uint4*)&s_x[(li[t] + s) * 40 + cb16];
                const float g = gw[t][s];
                float v0 = bflo(u.x), v1 = bfhi(u.x), v2 = bflo(u.y), v3 = bfhi(u.y);
                float v4 = bflo(u.z), v5 = bfhi(u.z), v6 = bflo(u.w), v7 = bfhi(u.w);
                if (s == 0) {
                    part[0] = g * v0; part[1] = g * v1; part[2] = g * v2; part[3] = g * v3;
                    part[4] = g * v4; part[5] = g * v5; part[6] = g * v6; part[7] = g * v7;
                } else {
                    part[0] += g * v0; part[1] += g * v1; part[2] += g * v2; part[3] += g * v3;
                    part[4] += g * v4; part[5] += g * v5; part[6] += g * v6; part[7] += g * v7;
                }
            }
            const float* rc = rout + (size_t)(cblk * 32 + c0l) * 9 + k;
            #pragma unroll
            for (int i = 0; i < 8; ++i)
                acc[i] += rc[i * 9] * part[i];
        }
        #pragma unroll
        for (int i = 0; i < 8; ++i)
            y0[(size_t)(cblk * 32 + c0l + i) * HW + gp] = f2bf(acc[i]);
    }
}

// ---------------------------------------------------------------------------
// R25: MFMA pointwise GEMM.  Weight fragments hoisted to registers BEFORE the
// barrier (pure dwordx4 loads of pre-split bf16; L2 latency overlaps staging).
// Non-atomic per-block stat partials; consumers fold them.
// Block: 4 waves x (16 o x 32 px).  Grid (384 px-blocks, 2 o-blocks) = 768.
// ---------------------------------------------------------------------------
template <int CIN>
__global__ __launch_bounds__(256, 4) void k_pw_mfma(
    const unsigned short* __restrict__ Aact,  // CIN x HW (bf16)
    const unsigned short* __restrict__ Whi,   // 128 x CIN (bf16)
    const unsigned short* __restrict__ Wlo,   // 128 x CIN (bf16)
    unsigned short* __restrict__ Z,           // 128 x HW (bf16)
    float* __restrict__ part)                 // 384 x 256 {sum,sumsq} partials
{
    constexpr int KC = CIN / 32;
    constexpr int RS = CIN + 8;               // pad keeps b128 16B-aligned
    __shared__ __align__(16) unsigned short s_b[32][RS];

    const int tid = threadIdx.x;
    const int l   = tid & 63;
    const int wv  = tid >> 6;
    const int px0 = blockIdx.x * 32;
    const int o0  = blockIdx.y * 64;

    // ---- stage act tile transposed: s_b[p][c ^ (((p>>4)&3)<<3)] ----
    {
        const int cs  = tid >> 1;             // 0..127
        const int pxb = (tid & 1) << 4;       // 0 or 16
        const int swz = (tid & 1) << 3;       // (p>>4)&3 == tid&1 here
        #pragma unroll
        for (int it = 0; it < CIN / 128; ++it) {
            const int c = cs + it * 128;
            const uint4* src = (const uint4*)(Aact + (size_t)c * HW + px0 + pxb);
            uint4 u0 = src[0];
            uint4 u1 = src[1];
            const int sc = c ^ swz;
            unsigned int wd[8] = {u0.x, u0.y, u0.z, u0.w, u1.x, u1.y, u1.z, u1.w};
            #pragma unroll
            for (int e = 0; e < 8; ++e) {
                s_b[pxb + 2 * e    ][sc] = (unsigned short)(wd[e] & 0xffffu);
                s_b[pxb + 2 * e + 1][sc] = (unsigned short)(wd[e] >> 16);
            }
        }
    }

    // ---- hoist weight fragments into registers (overlaps staging/barrier) ----
    // A-frag layout: row m = l&15, k = (l>>4)*8 + j
    const int orow = o0 + wv * 16 + (l & 15);
    const unsigned short* whp = Whi + (size_t)orow * CIN + ((l >> 4) << 3);
    const unsigned short* wlp = Wlo + (size_t)orow * CIN + ((l >> 4) << 3);
    bf16x8 wh[KC], wl[KC];
    #pragma unroll
    for (int kc = 0; kc < KC; ++kc) {
        wh[kc] = *(const bf16x8*)(whp + kc * 32);
        wl[kc] = *(const bf16x8*)(wlp + kc * 32);
    }

    __syncthreads();

    // ---- MFMA K-loop (fully unrolled, weights in regs) ----
    f32x4 acc[2] = { {0.f, 0.f, 0.f, 0.f}, {0.f, 0.f, 0.f, 0.f} };
    const int prow = l & 15;
    const int kg8  = l >> 4;
    #pragma unroll
    for (int kc = 0; kc < KC; ++kc) {
        #pragma unroll
        for (int ip = 0; ip < 2; ++ip) {
            const int col = kc * 32 + (((kg8 ^ ip) & 3) << 3);
            bf16x8 bfr = *(const bf16x8*)&s_b[ip * 16 + prow][col];
            acc[ip] = __builtin_amdgcn_mfma_f32_16x16x32_bf16(wh[kc], bfr, acc[ip], 0, 0, 0);
            acc[ip] = __builtin_amdgcn_mfma_f32_16x16x32_bf16(wl[kc], bfr, acc[ip], 0, 0, 0);
        }
    }

    // ---- epilogue: store Z (bf16) + per-block partial BN stats (no atomics) ----
    // D layout: col = l&15 (px), row m = (l>>4)*4 + r  (m89-verified)
    float* pp = part + (size_t)blockIdx.x * 256;
    const int obase = o0 + wv * 16 + ((l >> 4) << 2);
    #pragma unroll
    for (int r = 0; r < 4; ++r) {
        const int ch = obase + r;
        float v0 = acc[0][r];
        float v1 = acc[1][r];
        Z[(size_t)ch * HW + px0 + prow]      = f2bf(v0);
        Z[(size_t)ch * HW + px0 + 16 + prow] = f2bf(v1);
        float s = v0 + v1;
        float q = v0 * v0 + v1 * v1;
        s += __shfl_xor(s, 1, 64);  q += __shfl_xor(q, 1, 64);
        s += __shfl_xor(s, 2, 64);  q += __shfl_xor(q, 2, 64);
        s += __shfl_xor(s, 4, 64);  q += __shfl_xor(q, 4, 64);
        s += __shfl_xor(s, 8, 64);  q += __shfl_xor(q, 8, 64);
        if (prow == 0) {
            pp[2 * ch]     = s;
            pp[2 * ch + 1] = q;
        }
    }
}

// ---------------------------------------------------------------------------
// R25: fused stats-fold + BN+LeakyReLU + depthwise 3x3 (zero pad), with the
// channel stripe LDS-staged via uint4 loads.  Block = 1024 px of one channel;
// stages 9 halo rows (3.6 KB), zero-filled OOB rows and zeroed pads.
// ---------------------------------------------------------------------------
__global__ __launch_bounds__(256) void k_dw(
    const unsigned short* __restrict__ Zs,
    const float* __restrict__ part,  // 384 x 256 partials
    const float* __restrict__ g,
    const float* __restrict__ b,
    const float* __restrict__ dwgt,  // 128 x 9
    ushort4* __restrict__ D)
{
    __shared__ float rs[4], rq[4];
    __shared__ __align__(16) unsigned short s_z[9 * 200 + 8];  // 9 rows x (8 pad + 192)
    const int tid = threadIdx.x;
    const int bx  = blockIdx.x;
    const int c   = bx / 12;                  // 12 blocks per channel
    const int m   = bx - c * 12;
    const int g0  = m * 1024;                 // first px of this block
    const int r0  = g0 / Wimg;                // first output row (floor)

    // stage rows r0-1 .. r0+7 at s_z[rr*200 + 8 + col]; pads zeroed
    const unsigned short* zc = Zs + (size_t)c * HW;
    if (tid < 216) {
        const int rr = tid / 24;              // 0..8
        const int cc = (tid - rr * 24) * 8;   // col start (8 shorts / 16 B)
        const int gr = r0 - 1 + rr;
        uint4 u = make_uint4(0u, 0u, 0u, 0u);
        if (gr >= 0 && gr < Himg)
            u = *(const uint4*)(zc + (size_t)gr * Wimg + cc);
        *(uint4*)&s_z[rr * 200 + 8 + cc] = u;
    } else if (tid < 226) {
        // zero the 9 left-pads and the tail (each 8 shorts = 16 B)
        *(uint4*)&s_z[(tid - 216) * 200] = make_uint4(0u, 0u, 0u, 0u);
    }

    // fold this channel's partials
    float s = 0.0f, q = 0.0f;
    for (int bb = tid; bb < 384; bb += 256) {
        const float* pb = part + (size_t)bb * 256 + 2 * c;
        s += pb[0];
        q += pb[1];
    }
    #pragma unroll
    for (int off = 32; off > 0; off >>= 1) {
        s += __shfl_down(s, off, 64);
        q += __shfl_down(q, off, 64);
    }
    if ((tid & 63) == 0) { rs[tid >> 6] = s; rq[tid >> 6] = q; }
    __syncthreads();
    s = rs[0] + rs[1] + rs[2] + rs[3];
    q = rq[0] + rq[1] + rq[2] + rq[3];

    const float mu  = s * (1.0f / HW);
    const float var = q * (1.0f / HW) - mu * mu;
    const float sc  = g[c] * rsqrtf(var + 1e-5f);
    const float sh  = b[c] - mu * sc;

    float wk[9];
    #pragma unroll
    for (int k = 0; k < 9; ++k) wk[k] = dwgt[c * 9 + k];

    const int gg = g0 + tid * 4;              // first of 4 px
    const int h  = gg / Wimg;
    const int w0 = gg - h * Wimg;
    const int lr = h - (r0 - 1);              // local row in s_z (1..7)

    float v[3][6];
    #pragma unroll
    for (int ky = 0; ky < 3; ++ky) {
        const int hh  = h + ky - 1;
        const bool rin = (hh >= 0) && (hh < Himg);
        const unsigned short* sr = &s_z[(lr - 1 + ky) * 200 + 7 + w0];
        #pragma unroll
        for (int j = 0; j < 6; ++j) {
            const int ww = w0 - 1 + j;
            const bool in = rin && (ww >= 0) && (ww < Wimg);
            float z = bf2f(sr[j]);            // staged zeros make OOB reads safe
            float y = z * sc + sh;
            y = (y >= 0.0f) ? y : 0.01f * y;
            v[ky][j] = in ? y : 0.0f;
        }
    }

    ushort4 o;
    float oo[4];
    #pragma unroll
    for (int j = 0; j < 4; ++j) {
        float a = 0.0f;
        #pragma unroll
        for (int ky = 0; ky < 3; ++ky)
            #pragma unroll
            for (int kx = 0; kx < 3; ++kx)
                a += wk[ky * 3 + kx] * v[ky][j + kx];
        oo[j] = a;
    }
    o.x = f2bf(oo[0]); o.y = f2bf(oo[1]); o.z = f2bf(oo[2]); o.w = f2bf(oo[3]);
    D[bx * 256 + tid] = o;
}

// ---------------------------------------------------------------------------
// Fused stats-fold + BN+LeakyReLU, fp32 out.  grid = 1536.
// ---------------------------------------------------------------------------
__global__ __launch_bounds__(256) void k_final(
    const unsigned short* __restrict__ Zs,
    const float* __restrict__ part,  // 384 x 256 partials
    const float* __restrict__ g,
    const float* __restrict__ b,
    float4* __restrict__ out)
{
    __shared__ float rs[4], rq[4];
    const int tid = threadIdx.x;
    const int c   = blockIdx.x / 12;          // 12 blocks per channel

    float s = 0.0f, q = 0.0f;
    for (int bb = tid; bb < 384; bb += 256) {
        const float* pb = part + (size_t)bb * 256 + 2 * c;
        s += pb[0];
        q += pb[1];
    }
    #pragma unroll
    for (int off = 32; off > 0; off >>= 1) {
        s += __shfl_down(s, off, 64);
        q += __shfl_down(q, off, 64);
    }
    if ((tid & 63) == 0) { rs[tid >> 6] = s; rq[tid >> 6] = q; }
    __syncthreads();
    s = rs[0] + rs[1] + rs[2] + rs[3];
    q = rq[0] + rq[1] + rq[2] + rq[3];

    const float mu  = s * (1.0f / HW);
    const float var = q * (1.0f / HW) - mu * mu;
    const float sc  = g[c] * rsqrtf(var + 1e-5f);
    const float sh  = b[c] - mu * sc;

    const int f = blockIdx.x * 256 + tid;
    uint2 a = ((const uint2*)Zs)[f];
    float4 v;
    v.x = bflo(a.x) * sc + sh; v.x = (v.x >= 0.0f) ? v.x : 0.01f * v.x;
    v.y = bfhi(a.x) * sc + sh; v.y = (v.y >= 0.0f) ? v.y : 0.01f * v.y;
    v.z = bflo(a.y) * sc + sh; v.z = (v.z >= 0.0f) ? v.z : 0.01f * v.z;
    v.w = bfhi(a.y) * sc + sh; v.w = (v.w >= 0.0f) ? v.w : 0.01f * v.w;
    out[f] = v;
}

// ---------------------------------------------------------------------------
extern "C" void kernel_launch(void* const* d_in, const int* in_sizes, int n_in,
                              void* d_out, int out_size, void* d_ws, size_t ws_size,
                              hipStream_t stream) {
    const float* x   = (const float*)d_in[0];
    const float* xr  = (const float*)d_in[1];
    const float* ro  = (const float*)d_in[2];
    const float* wr  = (const float*)d_in[3];
    const float* gr  = (const float*)d_in[4];
    const float* br  = (const float*)d_in[5];
    const float* dw1 = (const float*)d_in[6];
    const float* pw1 = (const float*)d_in[7];
    const float* g1  = (const float*)d_in[8];
    const float* b1  = (const float*)d_in[9];
    const float* dw2 = (const float*)d_in[10];
    const float* pw2 = (const float*)d_in[11];
    const float* g2  = (const float*)d_in[12];
    const float* b2  = (const float*)d_in[13];

    unsigned short* WS = (unsigned short*)d_ws;
    unsigned short* y0 = WS;                  // 256 x HW bf16
    unsigned short* Z1 = WS + 3145728;        // 128 x HW bf16
    unsigned short* D  = WS + 4718592;        // 128 x HW bf16 (dw out, reused)
    unsigned short* Z2 = WS + 6291456;
    unsigned short* Z3 = WS + 7864320;
    unsigned short* W1h = WS + 9438720;       // 128x256 bf16 hi
    unsigned short* W1l = WS + 9471488;       // 128x256 bf16 lo
    unsigned short* W2h = WS + 9504256;       // 128x128
    unsigned short* W2l = WS + 9520640;
    unsigned short* W3h = WS + 9537024;
    unsigned short* W3l = WS + 9553408;
    // stat partials (384 x 256 fp32 = 384 KB) live in dead Z-slots:
    float* part1 = (float*)(WS + 6291456);    // Z2 slot (written later by pw2)
    float* part2 = (float*)WS;                // y0 slot (dead after pw1)
    float* part3 = (float*)WS;                // y0 slot (still dead)
    float* out = (float*)d_out;

    k_deform<<<dim3(8, 96), 256, 0, stream>>>(x, xr, ro, y0, wr, pw1, pw2,
                                              W1h, W1l, W2h, W2l, W3h, W3l);
    k_pw_mfma<256><<<dim3(384, 2), 256, 0, stream>>>(y0, W1h, W1l, Z1, part1);
    k_dw<<<1536, 256, 0, stream>>>(Z1, part1, gr, br, dw1, (ushort4*)D);
    k_pw_mfma<128><<<dim3(384, 2), 256, 0, stream>>>(D, W2h, W2l, Z2, part2);
    k_dw<<<1536, 256, 0, stream>>>(Z2, part2, g1, b1, dw2, (ushort4*)D);
    k_pw_mfma<128><<<dim3(384, 2), 256, 0, stream>>>(D, W3h, W3l, Z3, part3);
    k_final<<<1536, 256, 0, stream>>>(Z3, part3, g2, b2, (float4*)out);
}